// Round 6
// baseline (652.198 us; speedup 1.0000x reference)
//
#include <hip/hip_runtime.h>
#include <hip/hip_fp16.h>

#define N_NODES 100000
#define N_EDGES 1600000
#define IN_DIM 128
#define HIDDEN 16
#define OUT_DIM 40
#define QMAXF 255.0f

#define NB 512            // buckets
#define RPB 196           // rows per bucket
#define NB_USED 511
#define BUCKET_CAP 4096
#define SLICES 4
#define ACC_STRIDE 17     // LDS padding: spread atomics over all 32 banks
#define TILE 4096         // edges per bin block (64B es-store runs)
#define EPT 16
#define NBLK_BIN ((N_EDGES + TILE - 1) / TILE)  // 391

__device__ __forceinline__ float qd_one(float x, float noise, float rmin,
                                        float rscale, float inv) {
    float q = rintf((x - rmin) * rscale + noise - 0.5f);
    q = fminf(fmaxf(q, 0.0f), QMAXF);
    return q * inv + rmin;
}

// Sum SLICES fp16 partial z rows for node t into fp32 x[16]; nt loads.
__device__ __forceinline__ void load_zsum(const __half* __restrict__ zp,
                                          int t, float x[16]) {
#pragma unroll
    for (int i = 0; i < 16; ++i) x[i] = 0.0f;
#pragma unroll
    for (int s = 0; s < SLICES; ++s) {
        const unsigned* p = (const unsigned*)(zp + (size_t)s * N_NODES * HIDDEN +
                                              (size_t)t * HIDDEN);
#pragma unroll
        for (int h = 0; h < 8; ++h) {
            const unsigned u = __builtin_nontemporal_load(p + h);
            const float2 f = __half22float2(*(const __half2*)&u);
            x[2 * h] += f.x;
            x[2 * h + 1] += f.y;
        }
    }
}

// ---------------- edge binning (once; reused by all 3 SpMMs) ----------------

__global__ __launch_bounds__(512) void k_initcur(int* __restrict__ cursor) {
    const int i = threadIdx.x;
    if (i < NB) cursor[i] = i * BUCKET_CAP;
}

__global__ __launch_bounds__(256) void k_bin(
    const int* __restrict__ row, const int* __restrict__ col,
    const float* __restrict__ vals, int* __restrict__ cursor,
    long long* __restrict__ es) {
    __shared__ int hist[NB];
    __shared__ int psum[256];
    __shared__ int lofs[NB];
    __shared__ int lcur[NB];
    __shared__ int gbase[NB];
    __shared__ long long stage[TILE];
    __shared__ int dsti[TILE];

    const int tid = threadIdx.x;
    for (int i = tid; i < NB; i += 256) hist[i] = 0;
    __syncthreads();

    int bk[EPT];
    long long ev[EPT];
    const int e0 = blockIdx.x * TILE;
#pragma unroll
    for (int k = 0; k < EPT; ++k) {
        const int e = e0 + k * 256 + tid;
        if (e < N_EDGES) {
            const int r = __builtin_nontemporal_load(row + e);
            const int cc = __builtin_nontemporal_load(col + e);
            const float vv = __builtin_nontemporal_load(vals + e);
            const int b = r / RPB;
            bk[k] = b;
            const unsigned lo = (unsigned)(cc | ((r - b * RPB) << 17));
            ev[k] = (long long)(((unsigned long long)__float_as_uint(vv) << 32) |
                                lo);
            atomicAdd(&hist[b], 1);
        } else {
            bk[k] = -1;
        }
    }
    __syncthreads();

    const int h0 = hist[2 * tid], h1 = hist[2 * tid + 1];
    psum[tid] = h0 + h1;
    __syncthreads();
    for (int off = 1; off < 256; off <<= 1) {
        int x = (tid >= off) ? psum[tid - off] : 0;
        __syncthreads();
        psum[tid] += x;
        __syncthreads();
    }
    const int excl = (tid == 0) ? 0 : psum[tid - 1];
    lofs[2 * tid] = excl;
    lofs[2 * tid + 1] = excl + h0;
    lcur[2 * tid] = excl;
    lcur[2 * tid + 1] = excl + h0;
    if (h0) gbase[2 * tid] = atomicAdd(&cursor[2 * tid], h0);
    if (h1) gbase[2 * tid + 1] = atomicAdd(&cursor[2 * tid + 1], h1);
    __syncthreads();

#pragma unroll
    for (int k = 0; k < EPT; ++k) {
        if (bk[k] >= 0) {
            const int b = bk[k];
            const int lp = atomicAdd(&lcur[b], 1);
            stage[lp] = ev[k];
            dsti[lp] = gbase[b] + (lp - lofs[b]);
        }
    }
    __syncthreads();

    const int S = psum[255];
    for (int i = tid; i < S; i += 256)
        __builtin_nontemporal_store(stage[i], es + dsti[i]);
}

// SpMM: SLICES blocks/bucket; 2 threads/edge x 16B y-gather (dwordx4);
// es via nt loads (no L2 alloc -> y stays resident); LDS fp32 acc stride 17;
// nt fp16 partial writeback.
__global__ __launch_bounds__(256) void k_spmm_bin(
    const int* __restrict__ cursor, const long long* __restrict__ es,
    const __half* __restrict__ y, __half* __restrict__ zp) {
    __shared__ float acc[RPB * ACC_STRIDE];  // 13.3 KB
    const int b = blockIdx.x >> 2;
    const int sl = blockIdx.x & (SLICES - 1);
    for (int i = threadIdx.x; i < RPB * ACC_STRIDE; i += 256) acc[i] = 0.0f;
    __syncthreads();

    const int start = b * BUCKET_CAP;
    const int end = cursor[b];
    const int c = threadIdx.x & 1;  // half-row: halfs [c*8, c*8+8)
    for (int j = start + sl * 128 + (threadIdx.x >> 1); j < end; j += 512) {
        const long long e = __builtin_nontemporal_load(es + j);
        const unsigned lo = (unsigned)e;
        const float v = __uint_as_float((unsigned)((unsigned long long)e >> 32));
        const int cl = lo & 0x1FFFF;
        const int rr = (int)(lo >> 17);
        const uint4 hv = *(const uint4*)(y + (size_t)cl * HIDDEN + c * 8);
        const float2 f0 = __half22float2(*(const __half2*)&hv.x);
        const float2 f1 = __half22float2(*(const __half2*)&hv.y);
        const float2 f2 = __half22float2(*(const __half2*)&hv.z);
        const float2 f3 = __half22float2(*(const __half2*)&hv.w);
        float* ap = &acc[rr * ACC_STRIDE + c * 8];
        atomicAdd(ap + 0, v * f0.x);
        atomicAdd(ap + 1, v * f0.y);
        atomicAdd(ap + 2, v * f1.x);
        atomicAdd(ap + 3, v * f1.y);
        atomicAdd(ap + 4, v * f2.x);
        atomicAdd(ap + 5, v * f2.y);
        atomicAdd(ap + 6, v * f3.x);
        atomicAdd(ap + 7, v * f3.y);
    }
    __syncthreads();

    const int rowBase = b * RPB;
    const int nrows = (N_NODES - rowBase < RPB) ? (N_NODES - rowBase) : RPB;
    unsigned* zb = (unsigned*)(zp + (size_t)sl * N_NODES * HIDDEN +
                               (size_t)rowBase * HIDDEN);
    for (int i = threadIdx.x; i < nrows * 8; i += 256) {
        const int r = i >> 3;
        const int k2 = (i & 7) * 2;
        const __half2 h = __floats2half2_rn(acc[r * ACC_STRIDE + k2],
                                            acc[r * ACC_STRIDE + k2 + 1]);
        __builtin_nontemporal_store(*(const unsigned*)&h, zb + i);
    }
}

// ---------------- dense / quant kernels ------------------------------------

__global__ __launch_bounds__(256) void k_qd_gemm1(
    const float* __restrict__ feat, const float* __restrict__ noise,
    const float* __restrict__ W1, __half* __restrict__ y) {
    __shared__ float dqbuf[4][IN_DIM];
    const int lane = threadIdx.x & 63;
    const int wv = threadIdx.x >> 6;
    const int col = lane & 15;
    const int kg = lane >> 4;

    float w1r[32];
#pragma unroll
    for (int i = 0; i < 32; ++i) w1r[i] = W1[(kg * 32 + i) * HIDDEN + col];

    const int ngroups = N_NODES / 4;  // 25000
    for (int g = blockIdx.x; g < ngroups; g += gridDim.x) {
        const int node = g * 4 + wv;
        const unsigned long long xr = __builtin_nontemporal_load(
            (const unsigned long long*)(feat + (size_t)node * IN_DIM) + lane);
        const unsigned long long nr = __builtin_nontemporal_load(
            (const unsigned long long*)(noise + (size_t)node * IN_DIM) + lane);
        const float xx = __uint_as_float((unsigned)xr);
        const float xy = __uint_as_float((unsigned)(xr >> 32));
        const float nx = __uint_as_float((unsigned)nr);
        const float ny = __uint_as_float((unsigned)(nr >> 32));
        float m = fminf(xx, xy), M = fmaxf(xx, xy);
#pragma unroll
        for (int off = 1; off < 64; off <<= 1) {
            m = fminf(m, __shfl_xor(m, off));
            M = fmaxf(M, __shfl_xor(M, off));
        }
        const float rscale = QMAXF / (M - m);
        const float inv = (M - m) / QMAXF;
        float2 dq;
        dq.x = qd_one(xx, nx, m, rscale, inv);
        dq.y = qd_one(xy, ny, m, rscale, inv);
        ((float2*)dqbuf[wv])[lane] = dq;
        __syncthreads();
        float acc = 0.0f;
        const float* dqk = dqbuf[wv] + kg * 32;
#pragma unroll
        for (int i = 0; i < 32; ++i) acc += dqk[i] * w1r[i];
        acc += __shfl_xor(acc, 16);
        acc += __shfl_xor(acc, 32);
        if (lane < 16) y[(size_t)node * HIDDEN + lane] = __float2half(acc);
        __syncthreads();
    }
}

__global__ __launch_bounds__(256) void k_qd_gemm16(
    const __half* __restrict__ zp, const float* __restrict__ noise,
    const float* __restrict__ W2, __half* __restrict__ y) {
    __shared__ float w[HIDDEN * HIDDEN];
    w[threadIdx.x] = W2[threadIdx.x];
    __syncthreads();
    const int t = blockIdx.x * 256 + threadIdx.x;
    if (t >= N_NODES) return;
    float x[16], nz[16];
    load_zsum(zp, t, x);
    {
        const float4* nr = (const float4*)(noise + (size_t)t * HIDDEN);
#pragma unroll
        for (int i = 0; i < 4; ++i) ((float4*)nz)[i] = nr[i];
    }
#pragma unroll
    for (int i = 0; i < 16; ++i) x[i] = fmaxf(x[i], 0.0f);
    float m = x[0], M = x[0];
#pragma unroll
    for (int i = 1; i < 16; ++i) { m = fminf(m, x[i]); M = fmaxf(M, x[i]); }
    const float rscale = QMAXF / (M - m);
    const float inv = (M - m) / QMAXF;
    float acc[16];
#pragma unroll
    for (int j = 0; j < 16; ++j) acc[j] = 0.0f;
#pragma unroll
    for (int k = 0; k < 16; ++k) {
        const float d = qd_one(x[k], nz[k], m, rscale, inv);
        const float4* wr = (const float4*)(w + k * 16);
#pragma unroll
        for (int j4 = 0; j4 < 4; ++j4) {
            float4 ww = wr[j4];
            acc[4 * j4 + 0] += d * ww.x;
            acc[4 * j4 + 1] += d * ww.y;
            acc[4 * j4 + 2] += d * ww.z;
            acc[4 * j4 + 3] += d * ww.w;
        }
    }
    __half hb[16];
#pragma unroll
    for (int i = 0; i < 16; ++i) hb[i] = __float2half(acc[i]);
    float4* yr = (float4*)(y + (size_t)t * HIDDEN);
    yr[0] = ((float4*)hb)[0];
    yr[1] = ((float4*)hb)[1];
}

__global__ __launch_bounds__(256) void k_qd16(
    const __half* __restrict__ zp, const float* __restrict__ noise,
    __half* __restrict__ y) {
    const int t = blockIdx.x * 256 + threadIdx.x;
    if (t >= N_NODES) return;
    float x[16], nz[16];
    load_zsum(zp, t, x);
    {
        const float4* nr = (const float4*)(noise + (size_t)t * HIDDEN);
#pragma unroll
        for (int i = 0; i < 4; ++i) ((float4*)nz)[i] = nr[i];
    }
#pragma unroll
    for (int i = 0; i < 16; ++i) x[i] = fmaxf(x[i], 0.0f);
    float m = x[0], M = x[0];
#pragma unroll
    for (int i = 1; i < 16; ++i) { m = fminf(m, x[i]); M = fmaxf(M, x[i]); }
    const float rscale = QMAXF / (M - m);
    const float inv = (M - m) / QMAXF;
    __half hb[16];
#pragma unroll
    for (int i = 0; i < 16; ++i)
        hb[i] = __float2half(qd_one(x[i], nz[i], m, rscale, inv));
    float4* yr = (float4*)(y + (size_t)t * HIDDEN);
    yr[0] = ((float4*)hb)[0];
    yr[1] = ((float4*)hb)[1];
}

__global__ __launch_bounds__(256) void k_gemm_out(
    const __half* __restrict__ zp, const float* __restrict__ W3,
    float* __restrict__ out) {
    __shared__ float w[HIDDEN * OUT_DIM];
    for (int i = threadIdx.x; i < HIDDEN * OUT_DIM; i += 256) w[i] = W3[i];
    __syncthreads();
    const int t = blockIdx.x * 256 + threadIdx.x;
    if (t >= N_NODES) return;
    float x[16];
    load_zsum(zp, t, x);
    float acc[OUT_DIM];
#pragma unroll
    for (int j = 0; j < OUT_DIM; ++j) acc[j] = 0.0f;
#pragma unroll
    for (int k = 0; k < 16; ++k) {
        const float d = x[k];
        const float4* wr = (const float4*)(w + k * OUT_DIM);
#pragma unroll
        for (int j4 = 0; j4 < OUT_DIM / 4; ++j4) {
            float4 ww = wr[j4];
            acc[4 * j4 + 0] += d * ww.x;
            acc[4 * j4 + 1] += d * ww.y;
            acc[4 * j4 + 2] += d * ww.z;
            acc[4 * j4 + 3] += d * ww.w;
        }
    }
    float4* orow = (float4*)(out + (size_t)t * OUT_DIM);
#pragma unroll
    for (int i = 0; i < OUT_DIM / 4; ++i) orow[i] = ((float4*)acc)[i];
}

extern "C" void kernel_launch(void* const* d_in, const int* in_sizes, int n_in,
                              void* d_out, int out_size, void* d_ws,
                              size_t ws_size, hipStream_t stream) {
    const float* feat = (const float*)d_in[0];
    const int* row = (const int*)d_in[1];
    const int* col = (const int*)d_in[2];
    const float* vals = (const float*)d_in[3];
    const float* W1 = (const float*)d_in[4];
    const float* W2 = (const float*)d_in[5];
    const float* W3 = (const float*)d_in[6];
    const float* n1 = (const float*)d_in[7];
    const float* n2 = (const float*)d_in[8];
    const float* n3 = (const float*)d_in[9];
    float* out = (float*)d_out;

    __half* yh = (__half*)d_ws;                              // 3.2 MB
    __half* zp = yh + (size_t)N_NODES * HIDDEN;              // 12.8 MB
    int* cursor = (int*)(zp + (size_t)SLICES * N_NODES * HIDDEN);
    long long* es = (long long*)(cursor + NB);               // 16.8 MB

    const int nodeBlocks = (N_NODES + 255) / 256;

    k_initcur<<<1, 512, 0, stream>>>(cursor);
    k_bin<<<NBLK_BIN, 256, 0, stream>>>(row, col, vals, cursor, es);

    // Layer 1
    k_qd_gemm1<<<2500, 256, 0, stream>>>(feat, n1, W1, yh);
    k_spmm_bin<<<NB_USED * SLICES, 256, 0, stream>>>(cursor, es, yh, zp);

    // Layer 2
    k_qd_gemm16<<<nodeBlocks, 256, 0, stream>>>(zp, n2, W2, yh);
    k_spmm_bin<<<NB_USED * SLICES, 256, 0, stream>>>(cursor, es, yh, zp);

    // Layer 3
    k_qd16<<<nodeBlocks, 256, 0, stream>>>(zp, n3, yh);
    k_spmm_bin<<<NB_USED * SLICES, 256, 0, stream>>>(cursor, es, yh, zp);
    k_gemm_out<<<nodeBlocks, 256, 0, stream>>>(zp, W3, out);
}

// Round 8
// 280.937 us; speedup vs baseline: 2.3215x; 2.3215x over previous
//
#include <hip/hip_runtime.h>
#include <hip/hip_fp16.h>

#define N_NODES 100000
#define N_EDGES 1600000
#define IN_DIM 128
#define HIDDEN 16
#define OUT_DIM 40
#define QMAXF 255.0f

#define NB 512            // row buckets
#define RPB 196           // rows per bucket
#define NB_USED 511       // buckets actually populated (0..510)
#define BUCKET_CAP 4096   // mean fill 3136, 17 sigma headroom
#define TILE 4096         // edges per bin block
#define EPT 16            // edges/thread in k_bin
#define NBLK_BIN ((N_EDGES + TILE - 1) / TILE)  // 391
#define HALF_CAP 2560     // stage cap for 98-row half bucket (mean 1568, 25s)

typedef float vfloat4 __attribute__((ext_vector_type(4)));

__device__ __forceinline__ float qd_one(float x, float noise, float rmin,
                                        float rscale, float inv) {
    float q = rintf((x - rmin) * rscale + noise - 0.5f);
    q = fminf(fmaxf(q, 0.0f), QMAXF);
    return q * inv + rmin;
}

// ---------------- edge binning (once) ---------------------------------------

__global__ __launch_bounds__(512) void k_initcur(int* __restrict__ cursor) {
    const int i = threadIdx.x;
    if (i < NB) cursor[i] = i * BUCKET_CAP;
}

__global__ __launch_bounds__(256) void k_bin(
    const int* __restrict__ row, const int* __restrict__ col,
    const float* __restrict__ vals, int* __restrict__ cursor,
    long long* __restrict__ es) {
    __shared__ int hist[NB];
    __shared__ int psum[256];
    __shared__ int lofs[NB];
    __shared__ int lcur[NB];
    __shared__ int gbase[NB];
    __shared__ long long stage[TILE];
    __shared__ int dsti[TILE];

    const int tid = threadIdx.x;
    for (int i = tid; i < NB; i += 256) hist[i] = 0;
    __syncthreads();

    int bk[EPT];
    long long ev[EPT];
    const int e0 = blockIdx.x * TILE;
#pragma unroll
    for (int k = 0; k < EPT; ++k) {
        const int e = e0 + k * 256 + tid;
        if (e < N_EDGES) {
            const int r = __builtin_nontemporal_load(row + e);
            const int cc = __builtin_nontemporal_load(col + e);
            const float vv = __builtin_nontemporal_load(vals + e);
            const int b = r / RPB;
            bk[k] = b;
            const unsigned lo = (unsigned)(cc | ((r - b * RPB) << 17));
            ev[k] = (long long)(((unsigned long long)__float_as_uint(vv) << 32) |
                                lo);
            atomicAdd(&hist[b], 1);
        } else {
            bk[k] = -1;
        }
    }
    __syncthreads();

    const int h0 = hist[2 * tid], h1 = hist[2 * tid + 1];
    psum[tid] = h0 + h1;
    __syncthreads();
    for (int off = 1; off < 256; off <<= 1) {
        int x = (tid >= off) ? psum[tid - off] : 0;
        __syncthreads();
        psum[tid] += x;
        __syncthreads();
    }
    const int excl = (tid == 0) ? 0 : psum[tid - 1];
    lofs[2 * tid] = excl;
    lofs[2 * tid + 1] = excl + h0;
    lcur[2 * tid] = excl;
    lcur[2 * tid + 1] = excl + h0;
    if (h0) gbase[2 * tid] = atomicAdd(&cursor[2 * tid], h0);
    if (h1) gbase[2 * tid + 1] = atomicAdd(&cursor[2 * tid + 1], h1);
    __syncthreads();

#pragma unroll
    for (int k = 0; k < EPT; ++k) {
        if (bk[k] >= 0) {
            const int b = bk[k];
            const int lp = atomicAdd(&lcur[b], 1);
            stage[lp] = ev[k];
            dsti[lp] = gbase[b] + (lp - lofs[b]);
        }
    }
    __syncthreads();

    const int S = psum[255];
    for (int i = tid; i < S; i += 256)
        __builtin_nontemporal_store(stage[i], es + dsti[i]);
}

// In-LDS counting sort by row within each bucket (once). Writes back the
// bucket's edges in row-sorted order + per-row segment ends (rowEnd).
__global__ __launch_bounds__(256) void k_sort(
    const int* __restrict__ cursor, long long* __restrict__ es,
    int* __restrict__ rowEnd) {
    __shared__ int hist[256];
    __shared__ int psum[256];
    __shared__ int cur[256];
    __shared__ long long stage[BUCKET_CAP];  // 32 KB

    const int b = blockIdx.x;
    const int tid = threadIdx.x;
    const int start = b * BUCKET_CAP;
    const int cnt = cursor[b] - start;

    hist[tid] = 0;
    __syncthreads();

    long long ev[EPT];
    int rr[EPT];
#pragma unroll
    for (int k = 0; k < EPT; ++k) {
        const int i = k * 256 + tid;
        if (i < cnt) {
            ev[k] = es[start + i];
            rr[k] = (int)(((unsigned)ev[k]) >> 17);
            atomicAdd(&hist[rr[k]], 1);
        } else {
            rr[k] = -1;
        }
    }
    __syncthreads();

    // inclusive scan of hist over 256 entries
    psum[tid] = hist[tid];
    __syncthreads();
    for (int off = 1; off < 256; off <<= 1) {
        int x = (tid >= off) ? psum[tid - off] : 0;
        __syncthreads();
        psum[tid] += x;
        __syncthreads();
    }
    if (tid < RPB) rowEnd[b * RPB + tid] = start + psum[tid];
    cur[tid] = psum[tid] - hist[tid];  // exclusive
    __syncthreads();

#pragma unroll
    for (int k = 0; k < EPT; ++k) {
        if (rr[k] >= 0) {
            const int pos = atomicAdd(&cur[rr[k]], 1);
            stage[pos] = ev[k];
        }
    }
    __syncthreads();

    for (int i = tid; i < cnt; i += 256)
        __builtin_nontemporal_store(stage[i], es + start + i);
}

// SpMM: 2 blocks per bucket; block stages its contiguous row-sorted edge
// slice into LDS, each thread accumulates one (row, half-row) in registers
// with a 4-wide unrolled independent-gather loop. Zero atomics.
__global__ __launch_bounds__(256) void k_spmm3(
    const int* __restrict__ rowEnd, const long long* __restrict__ es,
    const __half* __restrict__ y, float* __restrict__ z) {
    __shared__ long long stage[HALF_CAP];  // 20.5 KB
    __shared__ int rp[100];                // row segment bounds (stage-rel)

    const int b = blockIdx.x >> 1;
    const int hb = blockIdx.x & 1;
    const int tid = threadIdx.x;
    const int r0 = hb * 98;               // first row of this half-bucket
    const int gb = b * RPB;
    const int bstart = b * BUCKET_CAP;

    // estart/eend for this half's contiguous edge slice
    __shared__ int sh_se[2];
    if (tid == 0) {
        sh_se[0] = (r0 == 0) ? bstart : rowEnd[gb + r0 - 1];
        sh_se[1] = rowEnd[gb + r0 + 97];
    }
    if (tid < 99) {
        // rp[i+1] = end of row r0+i (global); rebased below
        rp[tid + 1] = rowEnd[gb + r0 + tid];
    }
    __syncthreads();
    const int estart = sh_se[0];
    const int cnt = sh_se[1] - estart;
    if (tid == 0) rp[0] = estart;
    __syncthreads();

    for (int i = tid; i < cnt; i += 256)
        stage[i] = __builtin_nontemporal_load(es + estart + i);
    __syncthreads();

    if (tid >= 196) return;
    const int lr = tid >> 1;              // 0..97 local row
    const int h = tid & 1;                // half-row: halfs [h*8, h*8+8)
    const int grow = gb + r0 + lr;
    int j = rp[lr] - estart;
    const int je = rp[lr + 1] - estart;

    float acc[8];
#pragma unroll
    for (int i = 0; i < 8; ++i) acc[i] = 0.0f;

    for (; j + 4 <= je; j += 4) {
        const long long e0 = stage[j], e1 = stage[j + 1];
        const long long e2 = stage[j + 2], e3 = stage[j + 3];
        const uint4 a0 = *(const uint4*)(y + (size_t)(((unsigned)e0) & 0x1FFFF) * HIDDEN + h * 8);
        const uint4 a1 = *(const uint4*)(y + (size_t)(((unsigned)e1) & 0x1FFFF) * HIDDEN + h * 8);
        const uint4 a2 = *(const uint4*)(y + (size_t)(((unsigned)e2) & 0x1FFFF) * HIDDEN + h * 8);
        const uint4 a3 = *(const uint4*)(y + (size_t)(((unsigned)e3) & 0x1FFFF) * HIDDEN + h * 8);
        const float v0 = __uint_as_float((unsigned)((unsigned long long)e0 >> 32));
        const float v1 = __uint_as_float((unsigned)((unsigned long long)e1 >> 32));
        const float v2 = __uint_as_float((unsigned)((unsigned long long)e2 >> 32));
        const float v3 = __uint_as_float((unsigned)((unsigned long long)e3 >> 32));
        const unsigned* p0 = (const unsigned*)&a0;
        const unsigned* p1 = (const unsigned*)&a1;
        const unsigned* p2 = (const unsigned*)&a2;
        const unsigned* p3 = (const unsigned*)&a3;
#pragma unroll
        for (int q = 0; q < 4; ++q) {
            float2 f;
            f = __half22float2(*(const __half2*)&p0[q]);
            acc[2 * q] += v0 * f.x; acc[2 * q + 1] += v0 * f.y;
            f = __half22float2(*(const __half2*)&p1[q]);
            acc[2 * q] += v1 * f.x; acc[2 * q + 1] += v1 * f.y;
            f = __half22float2(*(const __half2*)&p2[q]);
            acc[2 * q] += v2 * f.x; acc[2 * q + 1] += v2 * f.y;
            f = __half22float2(*(const __half2*)&p3[q]);
            acc[2 * q] += v3 * f.x; acc[2 * q + 1] += v3 * f.y;
        }
    }
    for (; j < je; ++j) {
        const long long e = stage[j];
        const float v = __uint_as_float((unsigned)((unsigned long long)e >> 32));
        const uint4 a = *(const uint4*)(y + (size_t)(((unsigned)e) & 0x1FFFF) * HIDDEN + h * 8);
        const unsigned* p = (const unsigned*)&a;
#pragma unroll
        for (int q = 0; q < 4; ++q) {
            const float2 f = __half22float2(*(const __half2*)&p[q]);
            acc[2 * q] += v * f.x;
            acc[2 * q + 1] += v * f.y;
        }
    }

    if (grow < N_NODES) {
        vfloat4* zr = (vfloat4*)(z + (size_t)grow * HIDDEN + h * 8);
        __builtin_nontemporal_store(*(const vfloat4*)&acc[0], zr);
        __builtin_nontemporal_store(*(const vfloat4*)&acc[4], zr + 1);
    }
}

// ---------------- dense / quant kernels ------------------------------------

__global__ __launch_bounds__(256) void k_qd_gemm1(
    const float* __restrict__ feat, const float* __restrict__ noise,
    const float* __restrict__ W1, __half* __restrict__ y) {
    __shared__ float dqbuf[4][IN_DIM];
    const int lane = threadIdx.x & 63;
    const int wv = threadIdx.x >> 6;
    const int col = lane & 15;
    const int kg = lane >> 4;

    float w1r[32];
#pragma unroll
    for (int i = 0; i < 32; ++i) w1r[i] = W1[(kg * 32 + i) * HIDDEN + col];

    const int ngroups = N_NODES / 4;  // 25000
    for (int g = blockIdx.x; g < ngroups; g += gridDim.x) {
        const int node = g * 4 + wv;
        const unsigned long long xr = __builtin_nontemporal_load(
            (const unsigned long long*)(feat + (size_t)node * IN_DIM) + lane);
        const unsigned long long nr = __builtin_nontemporal_load(
            (const unsigned long long*)(noise + (size_t)node * IN_DIM) + lane);
        const float xx = __uint_as_float((unsigned)xr);
        const float xy = __uint_as_float((unsigned)(xr >> 32));
        const float nx = __uint_as_float((unsigned)nr);
        const float ny = __uint_as_float((unsigned)(nr >> 32));
        float m = fminf(xx, xy), M = fmaxf(xx, xy);
#pragma unroll
        for (int off = 1; off < 64; off <<= 1) {
            m = fminf(m, __shfl_xor(m, off));
            M = fmaxf(M, __shfl_xor(M, off));
        }
        const float rscale = QMAXF / (M - m);
        const float inv = (M - m) / QMAXF;
        float2 dq;
        dq.x = qd_one(xx, nx, m, rscale, inv);
        dq.y = qd_one(xy, ny, m, rscale, inv);
        ((float2*)dqbuf[wv])[lane] = dq;
        __syncthreads();
        float acc = 0.0f;
        const float* dqk = dqbuf[wv] + kg * 32;
#pragma unroll
        for (int i = 0; i < 32; ++i) acc += dqk[i] * w1r[i];
        acc += __shfl_xor(acc, 16);
        acc += __shfl_xor(acc, 32);
        if (lane < 16) y[(size_t)node * HIDDEN + lane] = __float2half(acc);
        __syncthreads();
    }
}

__global__ __launch_bounds__(256) void k_qd_gemm16(
    const float* __restrict__ zin, const float* __restrict__ noise,
    const float* __restrict__ W2, __half* __restrict__ y) {
    __shared__ float w[HIDDEN * HIDDEN];
    w[threadIdx.x] = W2[threadIdx.x];
    __syncthreads();
    const int t = blockIdx.x * 256 + threadIdx.x;
    if (t >= N_NODES) return;
    float x[16], nz[16];
    {
        const float4* zr = (const float4*)(zin + (size_t)t * HIDDEN);
        const float4* nr = (const float4*)(noise + (size_t)t * HIDDEN);
#pragma unroll
        for (int i = 0; i < 4; ++i) {
            ((float4*)x)[i] = zr[i];
            ((float4*)nz)[i] = nr[i];
        }
    }
#pragma unroll
    for (int i = 0; i < 16; ++i) x[i] = fmaxf(x[i], 0.0f);
    float m = x[0], M = x[0];
#pragma unroll
    for (int i = 1; i < 16; ++i) { m = fminf(m, x[i]); M = fmaxf(M, x[i]); }
    const float rscale = QMAXF / (M - m);
    const float inv = (M - m) / QMAXF;
    float acc[16];
#pragma unroll
    for (int j = 0; j < 16; ++j) acc[j] = 0.0f;
#pragma unroll
    for (int k = 0; k < 16; ++k) {
        const float d = qd_one(x[k], nz[k], m, rscale, inv);
        const float4* wr = (const float4*)(w + k * 16);
#pragma unroll
        for (int j4 = 0; j4 < 4; ++j4) {
            float4 ww = wr[j4];
            acc[4 * j4 + 0] += d * ww.x;
            acc[4 * j4 + 1] += d * ww.y;
            acc[4 * j4 + 2] += d * ww.z;
            acc[4 * j4 + 3] += d * ww.w;
        }
    }
    __half hb[16];
#pragma unroll
    for (int i = 0; i < 16; ++i) hb[i] = __float2half(acc[i]);
    float4* yr = (float4*)(y + (size_t)t * HIDDEN);
    yr[0] = ((float4*)hb)[0];
    yr[1] = ((float4*)hb)[1];
}

__global__ __launch_bounds__(256) void k_qd16(
    const float* __restrict__ zin, const float* __restrict__ noise,
    __half* __restrict__ y) {
    const int t = blockIdx.x * 256 + threadIdx.x;
    if (t >= N_NODES) return;
    float x[16], nz[16];
    {
        const float4* zr = (const float4*)(zin + (size_t)t * HIDDEN);
        const float4* nr = (const float4*)(noise + (size_t)t * HIDDEN);
#pragma unroll
        for (int i = 0; i < 4; ++i) {
            ((float4*)x)[i] = zr[i];
            ((float4*)nz)[i] = nr[i];
        }
    }
#pragma unroll
    for (int i = 0; i < 16; ++i) x[i] = fmaxf(x[i], 0.0f);
    float m = x[0], M = x[0];
#pragma unroll
    for (int i = 1; i < 16; ++i) { m = fminf(m, x[i]); M = fmaxf(M, x[i]); }
    const float rscale = QMAXF / (M - m);
    const float inv = (M - m) / QMAXF;
    __half hb[16];
#pragma unroll
    for (int i = 0; i < 16; ++i)
        hb[i] = __float2half(qd_one(x[i], nz[i], m, rscale, inv));
    float4* yr = (float4*)(y + (size_t)t * HIDDEN);
    yr[0] = ((float4*)hb)[0];
    yr[1] = ((float4*)hb)[1];
}

__global__ __launch_bounds__(256) void k_gemm_out(
    const float* __restrict__ z, const float* __restrict__ W3,
    float* __restrict__ out) {
    __shared__ float w[HIDDEN * OUT_DIM];
    for (int i = threadIdx.x; i < HIDDEN * OUT_DIM; i += 256) w[i] = W3[i];
    __syncthreads();
    const int t = blockIdx.x * 256 + threadIdx.x;
    if (t >= N_NODES) return;
    float x[16];
    {
        const float4* zr = (const float4*)(z + (size_t)t * HIDDEN);
#pragma unroll
        for (int i = 0; i < 4; ++i) ((float4*)x)[i] = zr[i];
    }
    float acc[OUT_DIM];
#pragma unroll
    for (int j = 0; j < OUT_DIM; ++j) acc[j] = 0.0f;
#pragma unroll
    for (int k = 0; k < 16; ++k) {
        const float d = x[k];
        const float4* wr = (const float4*)(w + k * OUT_DIM);
#pragma unroll
        for (int j4 = 0; j4 < OUT_DIM / 4; ++j4) {
            float4 ww = wr[j4];
            acc[4 * j4 + 0] += d * ww.x;
            acc[4 * j4 + 1] += d * ww.y;
            acc[4 * j4 + 2] += d * ww.z;
            acc[4 * j4 + 3] += d * ww.w;
        }
    }
    float4* orow = (float4*)(out + (size_t)t * OUT_DIM);
#pragma unroll
    for (int i = 0; i < OUT_DIM / 4; ++i) orow[i] = ((float4*)acc)[i];
}

extern "C" void kernel_launch(void* const* d_in, const int* in_sizes, int n_in,
                              void* d_out, int out_size, void* d_ws,
                              size_t ws_size, hipStream_t stream) {
    const float* feat = (const float*)d_in[0];
    const int* row = (const int*)d_in[1];
    const int* col = (const int*)d_in[2];
    const float* vals = (const float*)d_in[3];
    const float* W1 = (const float*)d_in[4];
    const float* W2 = (const float*)d_in[5];
    const float* W3 = (const float*)d_in[6];
    const float* n1 = (const float*)d_in[7];
    const float* n2 = (const float*)d_in[8];
    const float* n3 = (const float*)d_in[9];
    float* out = (float*)d_out;

    __half* yh = (__half*)d_ws;                           // 3.2 MB
    float* z = (float*)(yh + (size_t)N_NODES * HIDDEN);   // 6.4 MB
    int* cursor = (int*)(z + (size_t)N_NODES * HIDDEN);   // NB ints
    int* rowEnd = cursor + NB;                            // NB*RPB ints (0.4MB)
    long long* es = (long long*)(rowEnd + NB * RPB);      // 16.8 MB

    const int nodeBlocks = (N_NODES + 255) / 256;

    // --- build row-sorted bucketed edge list (once) ---
    k_initcur<<<1, 512, 0, stream>>>(cursor);
    k_bin<<<NBLK_BIN, 256, 0, stream>>>(row, col, vals, cursor, es);
    k_sort<<<NB_USED, 256, 0, stream>>>(cursor, es, rowEnd);

    // Layer 1
    k_qd_gemm1<<<2500, 256, 0, stream>>>(feat, n1, W1, yh);
    k_spmm3<<<NB_USED * 2, 256, 0, stream>>>(rowEnd, es, yh, z);

    // Layer 2
    k_qd_gemm16<<<nodeBlocks, 256, 0, stream>>>(z, n2, W2, yh);
    k_spmm3<<<NB_USED * 2, 256, 0, stream>>>(rowEnd, es, yh, z);

    // Layer 3
    k_qd16<<<nodeBlocks, 256, 0, stream>>>(z, n3, yh);
    k_spmm3<<<NB_USED * 2, 256, 0, stream>>>(rowEnd, es, yh, z);
    k_gemm_out<<<nodeBlocks, 256, 0, stream>>>(z, W3, out);
}